// Round 15
// baseline (359.049 us; speedup 1.0000x reference)
//
#include <hip/hip_runtime.h>
#include <hip/hip_bf16.h>
#include <stdint.h>

typedef __attribute__((ext_vector_type(8))) short bf16x8;
typedef __attribute__((ext_vector_type(4))) float f32x4;
typedef __attribute__((ext_vector_type(16))) float f32x16;
typedef unsigned short u16;
typedef unsigned int u32;
typedef const __attribute__((address_space(1))) u32* gp_t;
typedef __attribute__((address_space(3))) u32* lp_t;

#define HD 128
#define NH 16
#define SEQ 2048
#define PASTN 2048
#define FULLS 4096
#define DM 2048

__device__ __forceinline__ u16 f2b(float f){
  union { float f; u32 u; } v; v.f = f;
  return (u16)((v.u + 0x7fffu + ((v.u >> 16) & 1u)) >> 16);
}
__device__ __forceinline__ float b2f(u16 b){
  union { u32 u; float f; } v; v.u = ((u32)b) << 16;
  return v.f;
}
__device__ __forceinline__ u32 cvtpk(float lo, float hi){
  u32 r; asm("v_cvt_pk_bf16_f32 %0, %1, %2" : "=v"(r) : "v"(lo), "v"(hi)); return r;
}
__device__ __forceinline__ f32x16 zero16(){ f32x16 z = {}; return z; }

// ------- fused fp32->bf16 convert of x, Wq, Wk, Wv, Wo (one launch) -------
__global__ void k_conv5(const float* __restrict__ sx,
                        const float* __restrict__ s1, const float* __restrict__ s2,
                        const float* __restrict__ s3, const float* __restrict__ s4,
                        u16* __restrict__ dx,
                        u16* __restrict__ d1, u16* __restrict__ d2,
                        u16* __restrict__ d3, u16* __restrict__ d4)
{
  const int total = 2097152 + 4 * 1048576;
  int i = blockIdx.x * blockDim.x + threadIdx.x;
  int stride = gridDim.x * blockDim.x;
  for (; i < total; i += stride){
    const float* s; u16* d; int off;
    if (i < 2097152){ s = sx; d = dx; off = i; }
    else {
      int t = i - 2097152;
      int seg = t >> 20; off = t & 1048575;
      s = (seg == 0) ? s1 : (seg == 1) ? s2 : (seg == 2) ? s3 : s4;
      d = (seg == 0) ? d1 : (seg == 1) ? d2 : (seg == 2) ? d3 : d4;
    }
    float4 v = ((const float4*)s)[off];
    ushort4 o = { f2b(v.x), f2b(v.y), f2b(v.z), f2b(v.w) };
    ((ushort4*)d)[off] = o;
  }
}

// ==== fused QKV bt-GEMM (256^2 8-phase) + past-KV copy blocks ====
__global__ __launch_bounds__(512, 1)
void k_qkv_fused(const u16* __restrict__ A,
                 const u16* __restrict__ Bq, const u16* __restrict__ Bk,
                 const u16* __restrict__ Bv,
                 u16* __restrict__ qb, u16* __restrict__ kbb,
                 u16* __restrict__ vtb,
                 float* __restrict__ outk, float* __restrict__ outv,
                 const float* __restrict__ pk, const float* __restrict__ pv)
{
  __shared__ char LDS[131072];
  const int bx = blockIdx.x;
  const int tid = threadIdx.x;

  if (bx >= 384){
    if (bx < 448){
      for (int i = (bx - 384) * 512 + tid; i < 2097152; i += 32768){
        int g = i * 4;
        int c = g & 127;
        int r = g >> 7;
        int bh = r >> 11;
        int s = r & 2047;
        long dst = ((long)bh * FULLS + s) * HD + c;
        float4 v = ((const float4*)pk)[i];
        *(float4*)(outk + dst) = v;
        ushort4 o = { f2b(v.x), f2b(v.y), f2b(v.z), f2b(v.w) };
        *(ushort4*)(kbb + dst) = o;
      }
    } else {
      float* ldsF = (float*)LDS;              // [64][129] padded
      for (int cc = 0; cc < 16; cc++){
        int c = ((bx - 448) << 4) + cc;
        int bh = c >> 5, s0 = (c & 31) << 6;
        const float* src = pv + ((long)bh * PASTN + s0) * HD;
        float* dsv = outv + ((long)bh * FULLS + s0) * HD;
#pragma unroll
        for (int p = 0; p < 4; p++){
          int idx = tid + p * 512;
          int row = idx >> 5, c4 = (idx & 31) << 2;
          float4 v = *(const float4*)(src + row * HD + c4);
          *(float4*)(dsv + row * HD + c4) = v;
          ldsF[row * 129 + c4 + 0] = v.x;
          ldsF[row * 129 + c4 + 1] = v.y;
          ldsF[row * 129 + c4 + 2] = v.z;
          ldsF[row * 129 + c4 + 3] = v.w;
        }
        __syncthreads();
        int d = tid >> 2, sb = (tid & 3) << 4;
        u16* dst = vtb + ((long)bh * HD + d) * FULLS + s0 + sb;
#pragma unroll
        for (int g = 0; g < 4; g++){
          ushort4 o = { f2b(ldsF[(sb + g * 4 + 0) * 129 + d]),
                        f2b(ldsF[(sb + g * 4 + 1) * 129 + d]),
                        f2b(ldsF[(sb + g * 4 + 2) * 129 + d]),
                        f2b(ldsF[(sb + g * 4 + 3) * 129 + d]) };
          *(ushort4*)(dst + g * 4) = o;
        }
        __syncthreads();
      }
    }
    return;
  }

  const int w = tid >> 6, l = tid & 63;
  const int wm = w >> 2, wn = w & 3;
  const int which = bx >> 7;
  const int r0 = bx & 127;
  const int m0 = (r0 & 15) * 256;
  const int n0s = (r0 >> 4) * 256;
  const u16* Bm = (which == 0) ? Bq : (which == 1) ? Bk : Bv;

  const int aoff0 = (((l >> 4) * 16) ^ ((l & 7) << 4));
  const int aoff1 = ((64 + (l >> 4) * 16) ^ ((l & 7) << 4));
  const char* ArdB = LDS + wm * 16384 + (l & 15) * 128;
  const char* BrdB = LDS + 65536 + (wn >> 1) * 16384 + (wn & 1) * 8192 + (l & 15) * 128;

  const int Pa = tid * 16, Pb = tid * 16 + 8192;
  const int ra = Pa >> 7, rb = Pb >> 7;
  const int sro1 = ra * 2048 + ((((Pa & 127) ^ ((ra & 7) << 4))) >> 1);
  const int sro2 = rb * 2048 + ((((Pb & 127) ^ ((rb & 7) << 4))) >> 1);
  char* sd1 = LDS + w * 1024;
  char* sd2 = LDS + w * 1024 + 8192;

  f32x4 acc[8][4] = {};

#define GLDS(SRC, DST) __builtin_amdgcn_global_load_lds((gp_t)(const void*)(SRC), (lp_t)(void*)(DST), 16, 0, 0)
#define STG(MAT, ROWB, C, REG) { const u16* s_ = (MAT) + (long)(ROWB) * 2048 + (C) * 64; \
    GLDS(s_ + sro1, sd1 + (REG)); GLDS(s_ + sro2, sd2 + (REG)); }
#define RDB(DST, PAR) { _Pragma("unroll") for (int nf = 0; nf < 4; nf++){ \
      DST[nf*2]   = *(const bf16x8*)(BrdB + (PAR)*32768 + nf*2048 + aoff0); \
      DST[nf*2+1] = *(const bf16x8*)(BrdB + (PAR)*32768 + nf*2048 + aoff1); } }
#define RDA(PAR, MF) \
      a0 = *(const bf16x8*)(ArdB + (PAR)*32768 + (MF)*2048 + aoff0); \
      a1 = *(const bf16x8*)(ArdB + (PAR)*32768 + (MF)*2048 + aoff1); \
      a2 = *(const bf16x8*)(ArdB + (PAR)*32768 + (MF+1)*2048 + aoff0); \
      a3 = *(const bf16x8*)(ArdB + (PAR)*32768 + (MF+1)*2048 + aoff1);
#define BARW { __builtin_amdgcn_s_barrier(); \
      asm volatile("s_waitcnt lgkmcnt(0)" ::: "memory"); \
      __builtin_amdgcn_sched_barrier(0); }
#define MM(BF, MF) { __builtin_amdgcn_s_setprio(1); \
      _Pragma("unroll") for (int nf = 0; nf < 4; nf++){ \
        acc[MF][nf]   = __builtin_amdgcn_mfma_f32_16x16x32_bf16(a0, BF[nf*2],   acc[MF][nf],   0,0,0); \
        acc[MF][nf]   = __builtin_amdgcn_mfma_f32_16x16x32_bf16(a1, BF[nf*2+1], acc[MF][nf],   0,0,0); \
        acc[MF+1][nf] = __builtin_amdgcn_mfma_f32_16x16x32_bf16(a2, BF[nf*2],   acc[MF+1][nf], 0,0,0); \
        acc[MF+1][nf] = __builtin_amdgcn_mfma_f32_16x16x32_bf16(a3, BF[nf*2+1], acc[MF+1][nf], 0,0,0); } \
      __builtin_amdgcn_s_setprio(0); }

  STG(A,  m0,        0, 0);
  STG(A,  m0 + 128,  0, 16384);
  STG(Bm, n0s,       0, 65536);
  STG(Bm, n0s + 128, 0, 81920);
  STG(Bm, n0s,       1, 98304);
  STG(Bm, n0s + 128, 1, 114688);
  asm volatile("s_waitcnt vmcnt(4)" ::: "memory");
  __builtin_amdgcn_s_barrier();

  for (int i = 0; i < 16; ++i){
    const int c1 = 2 * i + 1;
    const int cn = 2 * i + 2;
    const bool nlast = (i < 15);
    bf16x8 b0[8], b1[8];
    bf16x8 a0, a1, a2, a3;

    RDB(b0, 0); RDA(0, 0);
    STG(A, m0, c1, 32768);
    BARW; MM(b0, 0);
    __builtin_amdgcn_s_barrier();

    RDA(0, 2);
    STG(A, m0 + 128, c1, 49152);
    BARW; MM(b0, 2);
    __builtin_amdgcn_s_barrier();

    RDA(0, 4);
    if (nlast) STG(Bm, n0s, cn, 65536);
    BARW; MM(b0, 4);
    __builtin_amdgcn_s_barrier();

    RDA(0, 6);
    if (nlast) STG(Bm, n0s + 128, cn, 81920);
    BARW; MM(b0, 6);
    if (nlast) { asm volatile("s_waitcnt vmcnt(4)" ::: "memory"); }
    else       { asm volatile("s_waitcnt vmcnt(0)" ::: "memory"); }
    __builtin_amdgcn_s_barrier();

    RDB(b1, 1); RDA(1, 0);
    if (nlast) STG(A, m0, cn, 0);
    BARW; MM(b1, 0);
    __builtin_amdgcn_s_barrier();

    RDA(1, 2);
    if (nlast) STG(A, m0 + 128, cn, 16384);
    BARW; MM(b1, 2);
    __builtin_amdgcn_s_barrier();

    RDA(1, 4);
    if (nlast) STG(Bm, n0s, cn + 1, 98304);
    BARW; MM(b1, 4);
    __builtin_amdgcn_s_barrier();

    RDA(1, 6);
    if (nlast) STG(Bm, n0s + 128, cn + 1, 114688);
    BARW; MM(b1, 6);
    if (nlast) { asm volatile("s_waitcnt vmcnt(4)" ::: "memory"); }
    __builtin_amdgcn_s_barrier();
  }

#undef MM
#undef BARW
#undef RDA
#undef RDB
#undef STG
#undef GLDS

  const int rbase = m0 + wm * 128 + ((l >> 4) << 2);
  const int cb2 = n0s + wn * 64 + (l & 15);
#pragma unroll
  for (int mf = 0; mf < 8; mf++){
#pragma unroll
    for (int nf = 0; nf < 4; nf++){
      const int nl = cb2 + nf * 16;
      const int h = nl >> 7, dd = nl & 127;
      if (which == 2){
        const int mm = rbase + mf * 16;
        const int b = mm >> 11, s = mm & 2047;
        const int bh = b * NH + h;
        ushort4 pkv = { f2b(acc[mf][nf][0]), f2b(acc[mf][nf][1]), f2b(acc[mf][nf][2]), f2b(acc[mf][nf][3]) };
        *(ushort4*)(vtb + ((long)bh * HD + dd) * FULLS + PASTN + s) = pkv;
#pragma unroll
        for (int r = 0; r < 4; r++){
          long idx = ((long)bh * FULLS + PASTN + s + r) * HD + dd;
          outv[idx] = acc[mf][nf][r];
        }
      } else if (which == 1){
#pragma unroll
        for (int r = 0; r < 4; r++){
          const int mm = rbase + mf * 16 + r;
          const int b = mm >> 11, s = mm & 2047;
          long idx = (((long)(b * NH + h)) * FULLS + PASTN + s) * HD + dd;
          float v = acc[mf][nf][r];
          kbb[idx] = f2b(v);
          outk[idx] = v;
        }
      } else {
#pragma unroll
        for (int r = 0; r < 4; r++){
          const int mm = rbase + mf * 16 + r;
          const int b = mm >> 11, s = mm & 2047;
          qb[(((long)(b * NH + h)) * SEQ + s) * HD + dd] = f2b(acc[mf][nf][r]);
        }
      }
    }
  }
}

// ==== O-projection: 8-phase, BM=256 BN=128, grid 256 ====
__global__ __launch_bounds__(512, 1)
void k_gemm_o8(const u16* __restrict__ A, const u16* __restrict__ Bm,
               float* __restrict__ outf)
{
  __shared__ char LDS[98304];
  const int tid = threadIdx.x, w = tid >> 6, l = tid & 63;
  const int wm = w >> 2, wn = w & 3;
  const int m0 = (blockIdx.x & 15) * 256;
  const int n0 = (blockIdx.x >> 4) * 128;

  const int aoff0 = (((l >> 4) * 16) ^ ((l & 7) << 4));
  const int aoff1 = ((64 + (l >> 4) * 16) ^ ((l & 7) << 4));
  const char* ArdB = LDS + wm * 16384 + (l & 15) * 128;
  const char* BrdB = LDS + 65536 + wn * 4096 + (l & 15) * 128;

  const int Pa = tid * 16, Pb = tid * 16 + 8192;
  const int ra = Pa >> 7, rb = Pb >> 7;
  const int sro1 = ra * 2048 + ((((Pa & 127) ^ ((ra & 7) << 4))) >> 1);
  const int sro2 = rb * 2048 + ((((Pb & 127) ^ ((rb & 7) << 4))) >> 1);
  char* sd1 = LDS + w * 1024;
  char* sd2 = LDS + w * 1024 + 8192;

  f32x4 acc[8][2] = {};

#define GLDS(SRC, DST) __builtin_amdgcn_global_load_lds((gp_t)(const void*)(SRC), (lp_t)(void*)(DST), 16, 0, 0)
#define STG(MAT, ROWB, C, REG) { const u16* s_ = (MAT) + (long)(ROWB) * 2048 + (C) * 64; \
    GLDS(s_ + sro1, sd1 + (REG)); GLDS(s_ + sro2, sd2 + (REG)); }
#define RDB2(DST, PAR) { _Pragma("unroll") for (int nf = 0; nf < 2; nf++){ \
      DST[nf*2]   = *(const bf16x8*)(BrdB + (PAR)*16384 + nf*2048 + aoff0); \
      DST[nf*2+1] = *(const bf16x8*)(BrdB + (PAR)*16384 + nf*2048 + aoff1); } }
#define RDA(PAR, MF) \
      a0 = *(const bf16x8*)(ArdB + (PAR)*32768 + (MF)*2048 + aoff0); \
      a1 = *(const bf16x8*)(ArdB + (PAR)*32768 + (MF)*2048 + aoff1); \
      a2 = *(const bf16x8*)(ArdB + (PAR)*32768 + (MF+1)*2048 + aoff0); \
      a3 = *(const bf16x8*)(ArdB + (PAR)*32768 + (MF+1)*2048 + aoff1);
#define BARW { __builtin_amdgcn_s_barrier(); \
      asm volatile("s_waitcnt lgkmcnt(0)" ::: "memory"); \
      __builtin_amdgcn_sched_barrier(0); }
#define MM2(BF, MF) { __builtin_amdgcn_s_setprio(1); \
      _Pragma("unroll") for (int nf = 0; nf < 2; nf++){ \
        acc[MF][nf]   = __builtin_amdgcn_mfma_f32_16x16x32_bf16(a0, BF[nf*2],   acc[MF][nf],   0,0,0); \
        acc[MF][nf]   = __builtin_amdgcn_mfma_f32_16x16x32_bf16(a1, BF[nf*2+1], acc[MF][nf],   0,0,0); \
        acc[MF+1][nf] = __builtin_amdgcn_mfma_f32_16x16x32_bf16(a2, BF[nf*2],   acc[MF+1][nf], 0,0,0); \
        acc[MF+1][nf] = __builtin_amdgcn_mfma_f32_16x16x32_bf16(a3, BF[nf*2+1], acc[MF+1][nf], 0,0,0); } \
      __builtin_amdgcn_s_setprio(0); }

  STG(A,  m0,       0, 0);
  STG(A,  m0 + 128, 0, 16384);
  STG(Bm, n0,       0, 65536);
  STG(Bm, n0,       1, 81920);
  asm volatile("s_waitcnt vmcnt(2)" ::: "memory");
  __builtin_amdgcn_s_barrier();

  for (int i = 0; i < 16; ++i){
    const int c1 = 2 * i + 1;
    const int cn = 2 * i + 2;
    const bool nlast = (i < 15);
    bf16x8 b0[4], b1[4];
    bf16x8 a0, a1, a2, a3;

    RDB2(b0, 0); RDA(0, 0);
    STG(A, m0, c1, 32768);
    BARW; MM2(b0, 0);
    __builtin_amdgcn_s_barrier();

    RDA(0, 2);
    STG(A, m0 + 128, c1, 49152);
    BARW; MM2(b0, 2);
    __builtin_amdgcn_s_barrier();

    RDA(0, 4);
    if (nlast) STG(Bm, n0, cn, 65536);
    BARW; MM2(b0, 4);
    __builtin_amdgcn_s_barrier();

    RDA(0, 6);
    BARW; MM2(b0, 6);
    if (nlast) { asm volatile("s_waitcnt vmcnt(2)" ::: "memory"); }
    else       { asm volatile("s_waitcnt vmcnt(0)" ::: "memory"); }
    __builtin_amdgcn_s_barrier();

    RDB2(b1, 1); RDA(1, 0);
    if (nlast) STG(A, m0, cn, 0);
    BARW; MM2(b1, 0);
    __builtin_amdgcn_s_barrier();

    RDA(1, 2);
    if (nlast) STG(A, m0 + 128, cn, 16384);
    BARW; MM2(b1, 2);
    __builtin_amdgcn_s_barrier();

    RDA(1, 4);
    if (nlast) STG(Bm, n0, cn + 1, 81920);
    BARW; MM2(b1, 4);
    __builtin_amdgcn_s_barrier();

    RDA(1, 6);
    BARW; MM2(b1, 6);
    if (nlast) { asm volatile("s_waitcnt vmcnt(2)" ::: "memory"); }
    __builtin_amdgcn_s_barrier();
  }

#undef MM2
#undef BARW
#undef RDA
#undef RDB2
#undef STG
#undef GLDS

  const int rbase = m0 + wm * 128 + ((l >> 4) << 2);
  const int cb2 = n0 + wn * 32 + (l & 15);
#pragma unroll
  for (int mf = 0; mf < 8; mf++)
#pragma unroll
    for (int nf = 0; nf < 2; nf++){
      const int nn = cb2 + nf * 16;
#pragma unroll
      for (int r = 0; r < 4; r++)
        outf[(long)(rbase + mf * 16 + r) * DM + nn] = acc[mf][nf][r];
    }
}

// ------- flash attention: round-10 structure + l-via-MFMA (ones-column).
// ------- 4 waves x 32 q-rows, swapped QK^T, in-register softmax, T15
// ------- 2-state pipeline; row-sum now accumulated by mfma(pfrag, ones)
// ------- into accl (same C-layout as acc) -> no per-tile VALU rowsum,
// ------- no epilogue inv-shuffles; rescale multiplies accl alongside acc.
__global__ __launch_bounds__(256, 2)
void k_attn(const u16* __restrict__ qb, const u16* __restrict__ kb,
            const u16* __restrict__ vtb, u16* __restrict__ ab)
{
  __shared__ u16 Ks[2][64 * 128];
  __shared__ u16 Vs[2][128 * 64];
  const int tid = threadIdx.x, w = tid >> 6, l = tid & 63;
  const int lq = l & 31, hi = l >> 5;
  const int dd0 = blockIdx.x;
  const int xcd = dd0 & 7;
  const int j   = dd0 >> 3;
  const int ja = j >> 5, jb = (j >> 1) & 15, jc = j & 1;
  const int bh  = xcd * 4 + 2 * ja + jc;
  const int q0b = ((ja ^ jc) ? (15 - jb) : jb) << 7;
  const int qbase = q0b + w * 32;
  const int qpos = PASTN + qbase + lq;
  const u16* qhead = qb + (long)bh * SEQ * HD;
  const u16* khead = kb + (long)bh * FULLS * HD;
  const u16* vhead = vtb + (long)bh * HD * FULLS;

  const float qscale = 0.08838834764831845f * 1.4426950408889634f;
  bf16x8 qf[8];
#pragma unroll
  for (int ks = 0; ks < 8; ks++){
    bf16x8 tq = *(const bf16x8*)(qhead + (long)(qbase + lq) * HD + ks * 16 + hi * 8);
#pragma unroll
    for (int jj = 0; jj < 8; jj++) tq[jj] = (short)f2b(b2f((u16)tq[jj]) * qscale);
    qf[ks] = tq;
  }

  bf16x8 ones;
#pragma unroll
  for (int jj = 0; jj < 8; jj++) ones[jj] = (short)0x3F80;   // bf16 1.0

  const int kswz = (lq & 15) << 4;
  const int vswz = (lq & 7) << 4;
  const char* kaddr[8];
#pragma unroll
  for (int ks = 0; ks < 8; ks++)
    kaddr[ks] = (const char*)Ks + lq * 256 + ((ks * 32 + hi * 16) ^ kswz);
  const char* vaddr[4];
#pragma unroll
  for (int ks2 = 0; ks2 < 4; ks2++)
    vaddr[ks2] = (const char*)Vs + lq * 128 + ((ks2 * 32 + hi * 16) ^ vswz);

  int ksrcoff[4], vsrcoff[4];
#pragma unroll
  for (int it = 0; it < 4; it++){
    int P = it * 4096 + w * 1024 + l * 16;
    ksrcoff[it] = P ^ (((P >> 8) & 15) << 4);
    int row = P >> 7;
    int cb = (P & 127) ^ ((row & 7) << 4);
    vsrcoff[it] = row * 8192 + cb;
  }

  auto stageK = [&](int t, int bufo){
    const char* src = (const char*)khead + ((long)t << 14);
    char* dstb = (char*)Ks + bufo + w * 1024;
#pragma unroll
    for (int it = 0; it < 4; it++)
      __builtin_amdgcn_global_load_lds((gp_t)(const void*)(src + ksrcoff[it]),
                                       (lp_t)(void*)(dstb + it * 4096), 16, 0, 0);
  };
  auto stageV = [&](int t, int bufo){
    const char* src = (const char*)vhead + ((long)t << 7);
    char* dstb = (char*)Vs + bufo + w * 1024;
#pragma unroll
    for (int it = 0; it < 4; it++)
      __builtin_amdgcn_global_load_lds((gp_t)(const void*)(src + vsrcoff[it]),
                                       (lp_t)(void*)(dstb + it * 4096), 16, 0, 0);
  };

  f32x16 acc[4] = {};
  f32x16 accl = {};                  // row-sum accumulator (ones-column PV)
  float m_run = -1e30f;
  const int ntiles = (PASTN + q0b + 128) >> 6;

  auto finishPV = [&](f32x16& sp0, f32x16& sp1, int vbufo){
    float a0[8];
#pragma unroll
    for (int i = 0; i < 8; i++)
      a0[i] = fmaxf(fmaxf(sp0[i], sp0[i + 8]), fmaxf(sp1[i], sp1[i + 8]));
    float mx = fmaxf(fmaxf(fmaxf(a0[0], a0[1]), fmaxf(a0[2], a0[3])),
                     fmaxf(fmaxf(a0[4], a0[5]), fmaxf(a0[6], a0[7])));
    { float xa = mx, xb = mx;
      asm("v_permlane32_swap_b32 %0, %1" : "+v"(xa), "+v"(xb));
      mx = fmaxf(xa, xb); }

    if (!__all(mx <= m_run + 8.f)){
      float mnew = fmaxf(m_run, mx);
      float corr = __builtin_exp2f(m_run - mnew);
      m_run = mnew;
#pragma unroll
      for (int r = 0; r < 16; r++){
        int qlr = (r & 3) + 8 * (r >> 2) + 4 * hi;
        float cr = __shfl(corr, qlr);
#pragma unroll
        for (int d2 = 0; d2 < 4; d2++) acc[d2][r] *= cr;
        accl[r] *= cr;
      }
    }

#pragma unroll
    for (int r = 0; r < 16; r++){
      sp0[r] = __builtin_exp2f(sp0[r] - m_run);
      sp1[r] = __builtin_exp2f(sp1[r] - m_run);
    }

    bf16x8 pfrag[4];
#pragma unroll
    for (int kb2 = 0; kb2 < 2; kb2++){
      const f32x16& sp = kb2 ? sp1 : sp0;
#pragma unroll
      for (int half = 0; half < 2; half++){
        const int h8 = half * 8;
        u32 A0 = cvtpk(sp[h8 + 0], sp[h8 + 1]);
        u32 A1 = cvtpk(sp[h8 + 2], sp[h8 + 3]);
        u32 B0 = cvtpk(sp[h8 + 4], sp[h8 + 5]);
        u32 B1 = cvtpk(sp[h8 + 6], sp[h8 + 7]);
        asm("v_permlane32_swap_b32 %0, %1" : "+v"(A0), "+v"(B0));
        asm("v_permlane32_swap_b32 %0, %1" : "+v"(A1), "+v"(B1));
        union { u32 wd[4]; bf16x8 v; } F;
        F.wd[0] = A0; F.wd[1] = A1; F.wd[2] = B0; F.wd[3] = B1;
        pfrag[kb2 * 2 + half] = F.v;
      }
    }

    __builtin_amdgcn_s_setprio(1);
#pragma unroll
    for (int ks2 = 0; ks2 < 4; ks2++){
#pragma unroll
      for (int d2 = 0; d2 < 4; d2++){
        bf16x8 vf = *(const bf16x8*)(vaddr[ks2] + vbufo + d2 * 4096);
        acc[d2] = __builtin_amdgcn_mfma_f32_32x32x16_bf16(pfrag[ks2], vf, acc[d2], 0, 0, 0);
      }
      accl = __builtin_amdgcn_mfma_f32_32x32x16_bf16(pfrag[ks2], ones, accl, 0, 0, 0);
    }
    __builtin_amdgcn_s_setprio(0);
  };

#define QKT_MASK(T_, BUFC_, SC0_, SC1_)                                        \
  {                                                                            \
    SC0_ = zero16(); SC1_ = zero16();                                          \
    __builtin_amdgcn_s_setprio(1);                                             \
    _Pragma("unroll")                                                          \
    for (int ks = 0; ks < 8; ks++){                                            \
      bf16x8 kf0 = *(const bf16x8*)(kaddr[ks] + (BUFC_));                      \
      bf16x8 kf1 = *(const bf16x8*)(kaddr[ks] + (BUFC_) + 8192);               \
      SC0_ = __builtin_amdgcn_mfma_f32_32x32x16_bf16(kf0, qf[ks], SC0_, 0,0,0);\
      SC1_ = __builtin_amdgcn_mfma_f32_32x32x16_bf16(kf1, qf[ks], SC1_, 0,0,0);\
    }                                                                          \
    __builtin_amdgcn_s_setprio(0);                                             \
    const int kvb_ = (T_) * 64;                                                \
    if (kvb_ + 63 > PASTN + qbase){                                            \
      _Pragma("unroll")                                                        \
      for (int r = 0; r < 16; r++){                                            \
        int key = kvb_ + (r & 3) + 8 * (r >> 2) + 4 * hi;                      \
        if (key > qpos) SC0_[r] = -1e30f;                                      \
        if (key + 32 > qpos) SC1_[r] = -1e30f;                                 \
      }                                                                        \
    }                                                                          \
  }

#define STEP(T_, BUFC_, SP0_, SP1_, SC0_, SC1_)                                \
  {                                                                            \
    if ((T_) + 1 < ntiles) stageK((T_) + 1, (BUFC_) ^ 16384);                  \
    QKT_MASK(T_, BUFC_, SC0_, SC1_);                                           \
    finishPV(SP0_, SP1_, (BUFC_) ^ 16384);                                     \
    __syncthreads();                                                           \
    if ((T_) + 1 < ntiles) stageV((T_) + 1, (BUFC_) ^ 16384);                  \
  }

  f32x16 PA0, PA1, PB0, PB1;

  stageK(0, 0); stageV(0, 0);
  __syncthreads();

  stageK(1, 16384);
  QKT_MASK(0, 0, PA0, PA1);
  __syncthreads();
  stageV(1, 16384);

  for (int t = 1; t + 2 < ntiles; t += 2){
    STEP(t,     16384, PA0, PA1, PB0, PB1);
    STEP(t + 1, 0,     PB0, PB1, PA0, PA1);
  }
  STEP(ntiles - 1, 16384, PA0, PA1, PB0, PB1);
  finishPV(PB0, PB1, 16384);

#undef STEP
#undef QKT_MASK

  // epilogue: accl[r] = l for q-row qlr(r,hi) (identical in every lane)
  const int b = bh >> 4, h = bh & 15;
#pragma unroll
  for (int r = 0; r < 16; r++){
    int qlr = (r & 3) + 8 * (r >> 2) + 4 * hi;
    float ir = 1.0f / accl[r];
    long rowbase = ((long)b * SEQ + (qbase + qlr)) * DM + h * HD;
#pragma unroll
    for (int d2 = 0; d2 < 4; d2++)
      ab[rowbase + d2 * 32 + lq] = f2b(acc[d2][r] * ir);
  }
}

extern "C" void kernel_launch(void* const* d_in, const int* in_sizes, int n_in,
                              void* d_out, int out_size, void* d_ws, size_t ws_size,
                              hipStream_t stream) {
  const float* x      = (const float*)d_in[0];
  const float* past_k = (const float*)d_in[1];
  const float* past_v = (const float*)d_in[2];
  const float* Wq     = (const float*)d_in[3];
  const float* Wk     = (const float*)d_in[4];
  const float* Wv     = (const float*)d_in[5];
  const float* Wo     = (const float*)d_in[6];

  float* out  = (float*)d_out;
  float* outk = out + 8388608;       // B*S*DM
  float* outv = out + 25165824;      // + B*NH*FULLS*HD

  char* ws = (char*)d_ws;
  u16* wqb = (u16*)ws;
  u16* wkb = (u16*)(ws + 8388608);
  u16* wvb = (u16*)(ws + 16777216);
  u16* wob = (u16*)(ws + 25165824);
  u16* xb  = (u16*)(ws + 33554432);
  u16* qb  = (u16*)(ws + 50331648);
  u16* kb  = (u16*)(ws + 67108864);
  u16* vtb = (u16*)(ws + 100663296);
  u16* ab  = xb;                     // alias: x consumed before attn writes

  k_conv5<<<2048, 256, 0, stream>>>(x, Wq, Wk, Wv, Wo, xb, wqb, wkb, wvb, wob);

  k_qkv_fused<<<512, 512, 0, stream>>>(xb, wqb, wkb, wvb,
                                       qb, kb, vtb, outk, outv,
                                       past_k, past_v);

  k_attn<<<512, 256, 0, stream>>>(qb, kb, vtb, ab);

  k_gemm_o8<<<256, 512, 0, stream>>>(ab, wob, out);
}

// Round 16
// 355.709 us; speedup vs baseline: 1.0094x; 1.0094x over previous
//
#include <hip/hip_runtime.h>
#include <hip/hip_bf16.h>
#include <stdint.h>

typedef __attribute__((ext_vector_type(8))) short bf16x8;
typedef __attribute__((ext_vector_type(4))) float f32x4;
typedef __attribute__((ext_vector_type(16))) float f32x16;
typedef unsigned short u16;
typedef unsigned int u32;
typedef const __attribute__((address_space(1))) u32* gp_t;
typedef __attribute__((address_space(3))) u32* lp_t;

#define HD 128
#define NH 16
#define SEQ 2048
#define PASTN 2048
#define FULLS 4096
#define DM 2048

__device__ __forceinline__ u16 f2b(float f){
  union { float f; u32 u; } v; v.f = f;
  return (u16)((v.u + 0x7fffu + ((v.u >> 16) & 1u)) >> 16);
}
__device__ __forceinline__ float b2f(u16 b){
  union { u32 u; float f; } v; v.u = ((u32)b) << 16;
  return v.f;
}
__device__ __forceinline__ u32 cvtpk(float lo, float hi){
  u32 r; asm("v_cvt_pk_bf16_f32 %0, %1, %2" : "=v"(r) : "v"(lo), "v"(hi)); return r;
}
__device__ __forceinline__ f32x16 zero16(){ f32x16 z = {}; return z; }

// ------- fused fp32->bf16 convert of x, Wq, Wk, Wv, Wo (one launch) -------
__global__ void k_conv5(const float* __restrict__ sx,
                        const float* __restrict__ s1, const float* __restrict__ s2,
                        const float* __restrict__ s3, const float* __restrict__ s4,
                        u16* __restrict__ dx,
                        u16* __restrict__ d1, u16* __restrict__ d2,
                        u16* __restrict__ d3, u16* __restrict__ d4)
{
  const int total = 2097152 + 4 * 1048576;
  int i = blockIdx.x * blockDim.x + threadIdx.x;
  int stride = gridDim.x * blockDim.x;
  for (; i < total; i += stride){
    const float* s; u16* d; int off;
    if (i < 2097152){ s = sx; d = dx; off = i; }
    else {
      int t = i - 2097152;
      int seg = t >> 20; off = t & 1048575;
      s = (seg == 0) ? s1 : (seg == 1) ? s2 : (seg == 2) ? s3 : s4;
      d = (seg == 0) ? d1 : (seg == 1) ? d2 : (seg == 2) ? d3 : d4;
    }
    float4 v = ((const float4*)s)[off];
    ushort4 o = { f2b(v.x), f2b(v.y), f2b(v.z), f2b(v.w) };
    ((ushort4*)d)[off] = o;
  }
}

// ==== fused QKV bt-GEMM (256^2 8-phase) + past-KV copy blocks ====
__global__ __launch_bounds__(512, 1)
void k_qkv_fused(const u16* __restrict__ A,
                 const u16* __restrict__ Bq, const u16* __restrict__ Bk,
                 const u16* __restrict__ Bv,
                 u16* __restrict__ qb, u16* __restrict__ kbb,
                 u16* __restrict__ vtb,
                 float* __restrict__ outk, float* __restrict__ outv,
                 const float* __restrict__ pk, const float* __restrict__ pv)
{
  __shared__ char LDS[131072];
  const int bx = blockIdx.x;
  const int tid = threadIdx.x;

  if (bx >= 384){
    if (bx < 448){
      for (int i = (bx - 384) * 512 + tid; i < 2097152; i += 32768){
        int g = i * 4;
        int c = g & 127;
        int r = g >> 7;
        int bh = r >> 11;
        int s = r & 2047;
        long dst = ((long)bh * FULLS + s) * HD + c;
        float4 v = ((const float4*)pk)[i];
        *(float4*)(outk + dst) = v;
        ushort4 o = { f2b(v.x), f2b(v.y), f2b(v.z), f2b(v.w) };
        *(ushort4*)(kbb + dst) = o;
      }
    } else {
      float* ldsF = (float*)LDS;              // [64][129] padded
      for (int cc = 0; cc < 16; cc++){
        int c = ((bx - 448) << 4) + cc;
        int bh = c >> 5, s0 = (c & 31) << 6;
        const float* src = pv + ((long)bh * PASTN + s0) * HD;
        float* dsv = outv + ((long)bh * FULLS + s0) * HD;
#pragma unroll
        for (int p = 0; p < 4; p++){
          int idx = tid + p * 512;
          int row = idx >> 5, c4 = (idx & 31) << 2;
          float4 v = *(const float4*)(src + row * HD + c4);
          *(float4*)(dsv + row * HD + c4) = v;
          ldsF[row * 129 + c4 + 0] = v.x;
          ldsF[row * 129 + c4 + 1] = v.y;
          ldsF[row * 129 + c4 + 2] = v.z;
          ldsF[row * 129 + c4 + 3] = v.w;
        }
        __syncthreads();
        int d = tid >> 2, sb = (tid & 3) << 4;
        u16* dst = vtb + ((long)bh * HD + d) * FULLS + s0 + sb;
#pragma unroll
        for (int g = 0; g < 4; g++){
          ushort4 o = { f2b(ldsF[(sb + g * 4 + 0) * 129 + d]),
                        f2b(ldsF[(sb + g * 4 + 1) * 129 + d]),
                        f2b(ldsF[(sb + g * 4 + 2) * 129 + d]),
                        f2b(ldsF[(sb + g * 4 + 3) * 129 + d]) };
          *(ushort4*)(dst + g * 4) = o;
        }
        __syncthreads();
      }
    }
    return;
  }

  const int w = tid >> 6, l = tid & 63;
  const int wm = w >> 2, wn = w & 3;
  const int which = bx >> 7;
  const int r0 = bx & 127;
  const int m0 = (r0 & 15) * 256;
  const int n0s = (r0 >> 4) * 256;
  const u16* Bm = (which == 0) ? Bq : (which == 1) ? Bk : Bv;

  const int aoff0 = (((l >> 4) * 16) ^ ((l & 7) << 4));
  const int aoff1 = ((64 + (l >> 4) * 16) ^ ((l & 7) << 4));
  const char* ArdB = LDS + wm * 16384 + (l & 15) * 128;
  const char* BrdB = LDS + 65536 + (wn >> 1) * 16384 + (wn & 1) * 8192 + (l & 15) * 128;

  const int Pa = tid * 16, Pb = tid * 16 + 8192;
  const int ra = Pa >> 7, rb = Pb >> 7;
  const int sro1 = ra * 2048 + ((((Pa & 127) ^ ((ra & 7) << 4))) >> 1);
  const int sro2 = rb * 2048 + ((((Pb & 127) ^ ((rb & 7) << 4))) >> 1);
  char* sd1 = LDS + w * 1024;
  char* sd2 = LDS + w * 1024 + 8192;

  f32x4 acc[8][4] = {};

#define GLDS(SRC, DST) __builtin_amdgcn_global_load_lds((gp_t)(const void*)(SRC), (lp_t)(void*)(DST), 16, 0, 0)
#define STG(MAT, ROWB, C, REG) { const u16* s_ = (MAT) + (long)(ROWB) * 2048 + (C) * 64; \
    GLDS(s_ + sro1, sd1 + (REG)); GLDS(s_ + sro2, sd2 + (REG)); }
#define RDB(DST, PAR) { _Pragma("unroll") for (int nf = 0; nf < 4; nf++){ \
      DST[nf*2]   = *(const bf16x8*)(BrdB + (PAR)*32768 + nf*2048 + aoff0); \
      DST[nf*2+1] = *(const bf16x8*)(BrdB + (PAR)*32768 + nf*2048 + aoff1); } }
#define RDA(PAR, MF) \
      a0 = *(const bf16x8*)(ArdB + (PAR)*32768 + (MF)*2048 + aoff0); \
      a1 = *(const bf16x8*)(ArdB + (PAR)*32768 + (MF)*2048 + aoff1); \
      a2 = *(const bf16x8*)(ArdB + (PAR)*32768 + (MF+1)*2048 + aoff0); \
      a3 = *(const bf16x8*)(ArdB + (PAR)*32768 + (MF+1)*2048 + aoff1);
#define BARW { __builtin_amdgcn_s_barrier(); \
      asm volatile("s_waitcnt lgkmcnt(0)" ::: "memory"); \
      __builtin_amdgcn_sched_barrier(0); }
#define MM(BF, MF) { __builtin_amdgcn_s_setprio(1); \
      _Pragma("unroll") for (int nf = 0; nf < 4; nf++){ \
        acc[MF][nf]   = __builtin_amdgcn_mfma_f32_16x16x32_bf16(a0, BF[nf*2],   acc[MF][nf],   0,0,0); \
        acc[MF][nf]   = __builtin_amdgcn_mfma_f32_16x16x32_bf16(a1, BF[nf*2+1], acc[MF][nf],   0,0,0); \
        acc[MF+1][nf] = __builtin_amdgcn_mfma_f32_16x16x32_bf16(a2, BF[nf*2],   acc[MF+1][nf], 0,0,0); \
        acc[MF+1][nf] = __builtin_amdgcn_mfma_f32_16x16x32_bf16(a3, BF[nf*2+1], acc[MF+1][nf], 0,0,0); } \
      __builtin_amdgcn_s_setprio(0); }

  STG(A,  m0,        0, 0);
  STG(A,  m0 + 128,  0, 16384);
  STG(Bm, n0s,       0, 65536);
  STG(Bm, n0s + 128, 0, 81920);
  STG(Bm, n0s,       1, 98304);
  STG(Bm, n0s + 128, 1, 114688);
  asm volatile("s_waitcnt vmcnt(4)" ::: "memory");
  __builtin_amdgcn_s_barrier();

  for (int i = 0; i < 16; ++i){
    const int c1 = 2 * i + 1;
    const int cn = 2 * i + 2;
    const bool nlast = (i < 15);
    bf16x8 b0[8], b1[8];
    bf16x8 a0, a1, a2, a3;

    RDB(b0, 0); RDA(0, 0);
    STG(A, m0, c1, 32768);
    BARW; MM(b0, 0);
    __builtin_amdgcn_s_barrier();

    RDA(0, 2);
    STG(A, m0 + 128, c1, 49152);
    BARW; MM(b0, 2);
    __builtin_amdgcn_s_barrier();

    RDA(0, 4);
    if (nlast) STG(Bm, n0s, cn, 65536);
    BARW; MM(b0, 4);
    __builtin_amdgcn_s_barrier();

    RDA(0, 6);
    if (nlast) STG(Bm, n0s + 128, cn, 81920);
    BARW; MM(b0, 6);
    if (nlast) { asm volatile("s_waitcnt vmcnt(4)" ::: "memory"); }
    else       { asm volatile("s_waitcnt vmcnt(0)" ::: "memory"); }
    __builtin_amdgcn_s_barrier();

    RDB(b1, 1); RDA(1, 0);
    if (nlast) STG(A, m0, cn, 0);
    BARW; MM(b1, 0);
    __builtin_amdgcn_s_barrier();

    RDA(1, 2);
    if (nlast) STG(A, m0 + 128, cn, 16384);
    BARW; MM(b1, 2);
    __builtin_amdgcn_s_barrier();

    RDA(1, 4);
    if (nlast) STG(Bm, n0s, cn + 1, 98304);
    BARW; MM(b1, 4);
    __builtin_amdgcn_s_barrier();

    RDA(1, 6);
    if (nlast) STG(Bm, n0s + 128, cn + 1, 114688);
    BARW; MM(b1, 6);
    if (nlast) { asm volatile("s_waitcnt vmcnt(4)" ::: "memory"); }
    __builtin_amdgcn_s_barrier();
  }

#undef MM
#undef BARW
#undef RDA
#undef RDB
#undef STG
#undef GLDS

  const int rbase = m0 + wm * 128 + ((l >> 4) << 2);
  const int cb2 = n0s + wn * 64 + (l & 15);
#pragma unroll
  for (int mf = 0; mf < 8; mf++){
#pragma unroll
    for (int nf = 0; nf < 4; nf++){
      const int nl = cb2 + nf * 16;
      const int h = nl >> 7, dd = nl & 127;
      if (which == 2){
        const int mm = rbase + mf * 16;
        const int b = mm >> 11, s = mm & 2047;
        const int bh = b * NH + h;
        ushort4 pkv = { f2b(acc[mf][nf][0]), f2b(acc[mf][nf][1]), f2b(acc[mf][nf][2]), f2b(acc[mf][nf][3]) };
        *(ushort4*)(vtb + ((long)bh * HD + dd) * FULLS + PASTN + s) = pkv;
#pragma unroll
        for (int r = 0; r < 4; r++){
          long idx = ((long)bh * FULLS + PASTN + s + r) * HD + dd;
          outv[idx] = acc[mf][nf][r];
        }
      } else if (which == 1){
#pragma unroll
        for (int r = 0; r < 4; r++){
          const int mm = rbase + mf * 16 + r;
          const int b = mm >> 11, s = mm & 2047;
          long idx = (((long)(b * NH + h)) * FULLS + PASTN + s) * HD + dd;
          float v = acc[mf][nf][r];
          kbb[idx] = f2b(v);
          outk[idx] = v;
        }
      } else {
#pragma unroll
        for (int r = 0; r < 4; r++){
          const int mm = rbase + mf * 16 + r;
          const int b = mm >> 11, s = mm & 2047;
          qb[(((long)(b * NH + h)) * SEQ + s) * HD + dd] = f2b(acc[mf][nf][r]);
        }
      }
    }
  }
}

// ==== O-projection: 8-phase, BM=256 BN=128, grid 256 ====
__global__ __launch_bounds__(512, 1)
void k_gemm_o8(const u16* __restrict__ A, const u16* __restrict__ Bm,
               float* __restrict__ outf)
{
  __shared__ char LDS[98304];
  const int tid = threadIdx.x, w = tid >> 6, l = tid & 63;
  const int wm = w >> 2, wn = w & 3;
  const int m0 = (blockIdx.x & 15) * 256;
  const int n0 = (blockIdx.x >> 4) * 128;

  const int aoff0 = (((l >> 4) * 16) ^ ((l & 7) << 4));
  const int aoff1 = ((64 + (l >> 4) * 16) ^ ((l & 7) << 4));
  const char* ArdB = LDS + wm * 16384 + (l & 15) * 128;
  const char* BrdB = LDS + 65536 + wn * 4096 + (l & 15) * 128;

  const int Pa = tid * 16, Pb = tid * 16 + 8192;
  const int ra = Pa >> 7, rb = Pb >> 7;
  const int sro1 = ra * 2048 + ((((Pa & 127) ^ ((ra & 7) << 4))) >> 1);
  const int sro2 = rb * 2048 + ((((Pb & 127) ^ ((rb & 7) << 4))) >> 1);
  char* sd1 = LDS + w * 1024;
  char* sd2 = LDS + w * 1024 + 8192;

  f32x4 acc[8][2] = {};

#define GLDS(SRC, DST) __builtin_amdgcn_global_load_lds((gp_t)(const void*)(SRC), (lp_t)(void*)(DST), 16, 0, 0)
#define STG(MAT, ROWB, C, REG) { const u16* s_ = (MAT) + (long)(ROWB) * 2048 + (C) * 64; \
    GLDS(s_ + sro1, sd1 + (REG)); GLDS(s_ + sro2, sd2 + (REG)); }
#define RDB2(DST, PAR) { _Pragma("unroll") for (int nf = 0; nf < 2; nf++){ \
      DST[nf*2]   = *(const bf16x8*)(BrdB + (PAR)*16384 + nf*2048 + aoff0); \
      DST[nf*2+1] = *(const bf16x8*)(BrdB + (PAR)*16384 + nf*2048 + aoff1); } }
#define RDA(PAR, MF) \
      a0 = *(const bf16x8*)(ArdB + (PAR)*32768 + (MF)*2048 + aoff0); \
      a1 = *(const bf16x8*)(ArdB + (PAR)*32768 + (MF)*2048 + aoff1); \
      a2 = *(const bf16x8*)(ArdB + (PAR)*32768 + (MF+1)*2048 + aoff0); \
      a3 = *(const bf16x8*)(ArdB + (PAR)*32768 + (MF+1)*2048 + aoff1);
#define BARW { __builtin_amdgcn_s_barrier(); \
      asm volatile("s_waitcnt lgkmcnt(0)" ::: "memory"); \
      __builtin_amdgcn_sched_barrier(0); }
#define MM2(BF, MF) { __builtin_amdgcn_s_setprio(1); \
      _Pragma("unroll") for (int nf = 0; nf < 2; nf++){ \
        acc[MF][nf]   = __builtin_amdgcn_mfma_f32_16x16x32_bf16(a0, BF[nf*2],   acc[MF][nf],   0,0,0); \
        acc[MF][nf]   = __builtin_amdgcn_mfma_f32_16x16x32_bf16(a1, BF[nf*2+1], acc[MF][nf],   0,0,0); \
        acc[MF+1][nf] = __builtin_amdgcn_mfma_f32_16x16x32_bf16(a2, BF[nf*2],   acc[MF+1][nf], 0,0,0); \
        acc[MF+1][nf] = __builtin_amdgcn_mfma_f32_16x16x32_bf16(a3, BF[nf*2+1], acc[MF+1][nf], 0,0,0); } \
      __builtin_amdgcn_s_setprio(0); }

  STG(A,  m0,       0, 0);
  STG(A,  m0 + 128, 0, 16384);
  STG(Bm, n0,       0, 65536);
  STG(Bm, n0,       1, 81920);
  asm volatile("s_waitcnt vmcnt(2)" ::: "memory");
  __builtin_amdgcn_s_barrier();

  for (int i = 0; i < 16; ++i){
    const int c1 = 2 * i + 1;
    const int cn = 2 * i + 2;
    const bool nlast = (i < 15);
    bf16x8 b0[4], b1[4];
    bf16x8 a0, a1, a2, a3;

    RDB2(b0, 0); RDA(0, 0);
    STG(A, m0, c1, 32768);
    BARW; MM2(b0, 0);
    __builtin_amdgcn_s_barrier();

    RDA(0, 2);
    STG(A, m0 + 128, c1, 49152);
    BARW; MM2(b0, 2);
    __builtin_amdgcn_s_barrier();

    RDA(0, 4);
    if (nlast) STG(Bm, n0, cn, 65536);
    BARW; MM2(b0, 4);
    __builtin_amdgcn_s_barrier();

    RDA(0, 6);
    BARW; MM2(b0, 6);
    if (nlast) { asm volatile("s_waitcnt vmcnt(2)" ::: "memory"); }
    else       { asm volatile("s_waitcnt vmcnt(0)" ::: "memory"); }
    __builtin_amdgcn_s_barrier();

    RDB2(b1, 1); RDA(1, 0);
    if (nlast) STG(A, m0, cn, 0);
    BARW; MM2(b1, 0);
    __builtin_amdgcn_s_barrier();

    RDA(1, 2);
    if (nlast) STG(A, m0 + 128, cn, 16384);
    BARW; MM2(b1, 2);
    __builtin_amdgcn_s_barrier();

    RDA(1, 4);
    if (nlast) STG(Bm, n0, cn + 1, 81920);
    BARW; MM2(b1, 4);
    __builtin_amdgcn_s_barrier();

    RDA(1, 6);
    BARW; MM2(b1, 6);
    if (nlast) { asm volatile("s_waitcnt vmcnt(2)" ::: "memory"); }
    __builtin_amdgcn_s_barrier();
  }

#undef MM2
#undef BARW
#undef RDA
#undef RDB2
#undef STG
#undef GLDS

  const int rbase = m0 + wm * 128 + ((l >> 4) << 2);
  const int cb2 = n0 + wn * 32 + (l & 15);
#pragma unroll
  for (int mf = 0; mf < 8; mf++)
#pragma unroll
    for (int nf = 0; nf < 2; nf++){
      const int nn = cb2 + nf * 16;
#pragma unroll
      for (int r = 0; r < 4; r++)
        outf[(long)(rbase + mf * 16 + r) * DM + nn] = acc[mf][nf][r];
    }
}

// ------- flash attention: round-10 proven version (best known) -------
__global__ __launch_bounds__(256, 2)
void k_attn(const u16* __restrict__ qb, const u16* __restrict__ kb,
            const u16* __restrict__ vtb, u16* __restrict__ ab)
{
  __shared__ u16 Ks[2][64 * 128];
  __shared__ u16 Vs[2][128 * 64];
  const int tid = threadIdx.x, w = tid >> 6, l = tid & 63;
  const int lq = l & 31, hi = l >> 5;
  const int dd0 = blockIdx.x;
  const int xcd = dd0 & 7;
  const int j   = dd0 >> 3;
  const int ja = j >> 5, jb = (j >> 1) & 15, jc = j & 1;
  const int bh  = xcd * 4 + 2 * ja + jc;
  const int q0b = ((ja ^ jc) ? (15 - jb) : jb) << 7;
  const int qbase = q0b + w * 32;
  const int qpos = PASTN + qbase + lq;
  const u16* qhead = qb + (long)bh * SEQ * HD;
  const u16* khead = kb + (long)bh * FULLS * HD;
  const u16* vhead = vtb + (long)bh * HD * FULLS;

  const float qscale = 0.08838834764831845f * 1.4426950408889634f;
  bf16x8 qf[8];
#pragma unroll
  for (int ks = 0; ks < 8; ks++){
    bf16x8 tq = *(const bf16x8*)(qhead + (long)(qbase + lq) * HD + ks * 16 + hi * 8);
#pragma unroll
    for (int jj = 0; jj < 8; jj++) tq[jj] = (short)f2b(b2f((u16)tq[jj]) * qscale);
    qf[ks] = tq;
  }

  const int kswz = (lq & 15) << 4;
  const int vswz = (lq & 7) << 4;
  const char* kaddr[8];
#pragma unroll
  for (int ks = 0; ks < 8; ks++)
    kaddr[ks] = (const char*)Ks + lq * 256 + ((ks * 32 + hi * 16) ^ kswz);
  const char* vaddr[4];
#pragma unroll
  for (int ks2 = 0; ks2 < 4; ks2++)
    vaddr[ks2] = (const char*)Vs + lq * 128 + ((ks2 * 32 + hi * 16) ^ vswz);

  int ksrcoff[4], vsrcoff[4];
#pragma unroll
  for (int it = 0; it < 4; it++){
    int P = it * 4096 + w * 1024 + l * 16;
    ksrcoff[it] = P ^ (((P >> 8) & 15) << 4);
    int row = P >> 7;
    int cb = (P & 127) ^ ((row & 7) << 4);
    vsrcoff[it] = row * 8192 + cb;
  }

  auto stageK = [&](int t, int bufo){
    const char* src = (const char*)khead + ((long)t << 14);
    char* dstb = (char*)Ks + bufo + w * 1024;
#pragma unroll
    for (int it = 0; it < 4; it++)
      __builtin_amdgcn_global_load_lds((gp_t)(const void*)(src + ksrcoff[it]),
                                       (lp_t)(void*)(dstb + it * 4096), 16, 0, 0);
  };
  auto stageV = [&](int t, int bufo){
    const char* src = (const char*)vhead + ((long)t << 7);
    char* dstb = (char*)Vs + bufo + w * 1024;
#pragma unroll
    for (int it = 0; it < 4; it++)
      __builtin_amdgcn_global_load_lds((gp_t)(const void*)(src + vsrcoff[it]),
                                       (lp_t)(void*)(dstb + it * 4096), 16, 0, 0);
  };

  f32x16 acc[4] = {};
  float m_run = -1e30f, l_run = 0.f;
  const int ntiles = (PASTN + q0b + 128) >> 6;

  auto finishPV = [&](f32x16& sp0, f32x16& sp1, int vbufo){
    float a0[8];
#pragma unroll
    for (int i = 0; i < 8; i++)
      a0[i] = fmaxf(fmaxf(sp0[i], sp0[i + 8]), fmaxf(sp1[i], sp1[i + 8]));
    float mx = fmaxf(fmaxf(fmaxf(a0[0], a0[1]), fmaxf(a0[2], a0[3])),
                     fmaxf(fmaxf(a0[4], a0[5]), fmaxf(a0[6], a0[7])));
    { float xa = mx, xb = mx;
      asm("v_permlane32_swap_b32 %0, %1" : "+v"(xa), "+v"(xb));
      mx = fmaxf(xa, xb); }

    if (!__all(mx <= m_run + 8.f)){
      float mnew = fmaxf(m_run, mx);
      float corr = __builtin_exp2f(m_run - mnew);
      m_run = mnew; l_run *= corr;
#pragma unroll
      for (int r = 0; r < 16; r++){
        int qlr = (r & 3) + 8 * (r >> 2) + 4 * hi;
        float cr = __shfl(corr, qlr);
#pragma unroll
        for (int d2 = 0; d2 < 4; d2++) acc[d2][r] *= cr;
      }
    }

    float rs = 0.f;
#pragma unroll
    for (int r = 0; r < 16; r++){
      sp0[r] = __builtin_exp2f(sp0[r] - m_run); rs += sp0[r];
      sp1[r] = __builtin_exp2f(sp1[r] - m_run); rs += sp1[r];
    }
    { float ra = rs, rb = rs;
      asm("v_permlane32_swap_b32 %0, %1" : "+v"(ra), "+v"(rb));
      l_run += ra + rb; }

    bf16x8 pfrag[4];
#pragma unroll
    for (int kb2 = 0; kb2 < 2; kb2++){
      const f32x16& sp = kb2 ? sp1 : sp0;
#pragma unroll
      for (int half = 0; half < 2; half++){
        const int h8 = half * 8;
        u32 A0 = cvtpk(sp[h8 + 0], sp[h8 + 1]);
        u32 A1 = cvtpk(sp[h8 + 2], sp[h8 + 3]);
        u32 B0 = cvtpk(sp[h8 + 4], sp[h8 + 5]);
        u32 B1 = cvtpk(sp[h8 + 6], sp[h8 + 7]);
        asm("v_permlane32_swap_b32 %0, %1" : "+v"(A0), "+v"(B0));
        asm("v_permlane32_swap_b32 %0, %1" : "+v"(A1), "+v"(B1));
        union { u32 wd[4]; bf16x8 v; } F;
        F.wd[0] = A0; F.wd[1] = A1; F.wd[2] = B0; F.wd[3] = B1;
        pfrag[kb2 * 2 + half] = F.v;
      }
    }

    __builtin_amdgcn_s_setprio(1);
#pragma unroll
    for (int ks2 = 0; ks2 < 4; ks2++)
#pragma unroll
      for (int d2 = 0; d2 < 4; d2++){
        bf16x8 vf = *(const bf16x8*)(vaddr[ks2] + vbufo + d2 * 4096);
        acc[d2] = __builtin_amdgcn_mfma_f32_32x32x16_bf16(pfrag[ks2], vf, acc[d2], 0, 0, 0);
      }
    __builtin_amdgcn_s_setprio(0);
  };

#define QKT_MASK(T_, BUFC_, SC0_, SC1_)                                        \
  {                                                                            \
    SC0_ = zero16(); SC1_ = zero16();                                          \
    __builtin_amdgcn_s_setprio(1);                                             \
    _Pragma("unroll")                                                          \
    for (int ks = 0; ks < 8; ks++){                                            \
      bf16x8 kf0 = *(const bf16x8*)(kaddr[ks] + (BUFC_));                      \
      bf16x8 kf1 = *(const bf16x8*)(kaddr[ks] + (BUFC_) + 8192);               \
      SC0_ = __builtin_amdgcn_mfma_f32_32x32x16_bf16(kf0, qf[ks], SC0_, 0,0,0);\
      SC1_ = __builtin_amdgcn_mfma_f32_32x32x16_bf16(kf1, qf[ks], SC1_, 0,0,0);\
    }                                                                          \
    __builtin_amdgcn_s_setprio(0);                                             \
    const int kvb_ = (T_) * 64;                                                \
    if (kvb_ + 63 > PASTN + qbase){                                            \
      _Pragma("unroll")                                                        \
      for (int r = 0; r < 16; r++){                                            \
        int key = kvb_ + (r & 3) + 8 * (r >> 2) + 4 * hi;                      \
        if (key > qpos) SC0_[r] = -1e30f;                                      \
        if (key + 32 > qpos) SC1_[r] = -1e30f;                                 \
      }                                                                        \
    }                                                                          \
  }

#define STEP(T_, BUFC_, SP0_, SP1_, SC0_, SC1_)                                \
  {                                                                            \
    if ((T_) + 1 < ntiles) stageK((T_) + 1, (BUFC_) ^ 16384);                  \
    QKT_MASK(T_, BUFC_, SC0_, SC1_);                                           \
    finishPV(SP0_, SP1_, (BUFC_) ^ 16384);                                     \
    __syncthreads();                                                           \
    if ((T_) + 1 < ntiles) stageV((T_) + 1, (BUFC_) ^ 16384);                  \
  }

  f32x16 PA0, PA1, PB0, PB1;

  stageK(0, 0); stageV(0, 0);
  __syncthreads();

  stageK(1, 16384);
  QKT_MASK(0, 0, PA0, PA1);
  __syncthreads();
  stageV(1, 16384);

  for (int t = 1; t + 2 < ntiles; t += 2){
    STEP(t,     16384, PA0, PA1, PB0, PB1);
    STEP(t + 1, 0,     PB0, PB1, PA0, PA1);
  }
  STEP(ntiles - 1, 16384, PA0, PA1, PB0, PB1);
  finishPV(PB0, PB1, 16384);

#undef STEP
#undef QKT_MASK

  float inv = 1.0f / l_run;
  const int b = bh >> 4, h = bh & 15;
#pragma unroll
  for (int r = 0; r < 16; r++){
    int qlr = (r & 3) + 8 * (r >> 2) + 4 * hi;
    float ir = __shfl(inv, qlr);
    long rowbase = ((long)b * SEQ + (qbase + qlr)) * DM + h * HD;
#pragma unroll
    for (int d2 = 0; d2 < 4; d2++)
      ab[rowbase + d2 * 32 + lq] = f2b(acc[d2][r] * ir);
  }
}

extern "C" void kernel_launch(void* const* d_in, const int* in_sizes, int n_in,
                              void* d_out, int out_size, void* d_ws, size_t ws_size,
                              hipStream_t stream) {
  const float* x      = (const float*)d_in[0];
  const float* past_k = (const float*)d_in[1];
  const float* past_v = (const float*)d_in[2];
  const float* Wq     = (const float*)d_in[3];
  const float* Wk     = (const float*)d_in[4];
  const float* Wv     = (const float*)d_in[5];
  const float* Wo     = (const float*)d_in[6];

  float* out  = (float*)d_out;
  float* outk = out + 8388608;       // B*S*DM
  float* outv = out + 25165824;      // + B*NH*FULLS*HD

  char* ws = (char*)d_ws;
  u16* wqb = (u16*)ws;
  u16* wkb = (u16*)(ws + 8388608);
  u16* wvb = (u16*)(ws + 16777216);
  u16* wob = (u16*)(ws + 25165824);
  u16* xb  = (u16*)(ws + 33554432);
  u16* qb  = (u16*)(ws + 50331648);
  u16* kb  = (u16*)(ws + 67108864);
  u16* vtb = (u16*)(ws + 100663296);
  u16* ab  = xb;                     // alias: x consumed before attn writes

  k_conv5<<<2048, 256, 0, stream>>>(x, Wq, Wk, Wv, Wo, xb, wqb, wkb, wvb, wob);

  k_qkv_fused<<<512, 512, 0, stream>>>(xb, wqb, wkb, wvb,
                                       qb, kb, vtb, outk, outv,
                                       past_k, past_v);

  k_attn<<<512, 256, 0, stream>>>(qb, kb, vtb, ab);

  k_gemm_o8<<<256, 512, 0, stream>>>(ab, wob, out);
}